// Round 9
// baseline (568.997 us; speedup 1.0000x reference)
//
#include <hip/hip_runtime.h>
#include <math.h>

// img (8, 3, 1024, 2048) fp32 -> same-shape fp32 output.
// Round-5 champion skeleton (1-row bodies, 8 waves, one non-draining barrier
// per row) + fully static unroll, packed float2 edges, VGPR<=64 pin.
#define Wd 2048
#define Hd 1024
#define BC 24
#define CH 32          // output rows per block chunk (y0 % 8 == 0)
#define NT 512         // 8 waves; lane owns 4 consecutive cols
#define NW 8
#define SROW (Wd + 8)  // LDS img row: col c at index c+4 (zero halo +-4)

__device__ __forceinline__ float4 f4s(float v) { return make_float4(v, v, v, v); }

// Exact-equivalent rewrite of the reference masking (verified r4-r6/r8, absmax 0).
__device__ __forceinline__ float masked_grad1(float g1, float g2, float g3) {
    const float HALF_T     = (float)(0.5 / 1023.0);
    const float GRD_BOTTOM = (float)(1.0 / 1023.0);
    const float GRD_UP     = (float)(4.0 / 1023.0);
    const float THIRD      = (float)(1.0 / 3.0);
    float m  = (g1 + g2 + g3) * THIRD;
    float lo = m - HALF_T;
    float hi = m + HALF_T;
    float a  = fabsf(g1);
    bool keep = (g1 >= lo) & (g1 <= hi) & (a >= GRD_BOTTOM) & (a <= GRD_UP);
    return keep ? g1 : 0.0f;
}

// One gradmap row: ce/lf/rt = x-halo; (a_k, b_k) give y diffs a_k - b_k.
__device__ __forceinline__ float4 grad_row(float4 ce, float4 lf, float4 rt,
        float4 a1, float4 b1, float4 a2, float4 b2, float4 a3, float4 b3) {
    const float K = 255.75f;  // 1023/4 exact
    float gx0 = masked_grad1(ce.y - lf.w, ce.z - lf.z, ce.w - lf.y);
    float gx1 = masked_grad1(ce.z - ce.x, ce.w - lf.w, rt.x - lf.z);
    float gx2 = masked_grad1(ce.w - ce.y, rt.x - ce.x, rt.y - lf.w);
    float gx3 = masked_grad1(rt.x - ce.z, rt.y - ce.y, rt.z - ce.x);
    float gy0 = masked_grad1(a1.x - b1.x, a2.x - b2.x, a3.x - b3.x);
    float gy1 = masked_grad1(a1.y - b1.y, a2.y - b2.y, a3.y - b3.y);
    float gy2 = masked_grad1(a1.z - b1.z, a2.z - b2.z, a3.z - b3.z);
    float gy3 = masked_grad1(a1.w - b1.w, a2.w - b2.w, a3.w - b3.w);
    float4 g;
    g.x = fmaxf(fabsf(gx0), fabsf(gy0)) * K;
    g.y = fmaxf(fabsf(gx1), fabsf(gy1)) * K;
    g.z = fmaxf(fabsf(gx2), fabsf(gy2)) * K;
    g.w = fmaxf(fabsf(gx3), fabsf(gy3)) * K;
    return g;
}

struct State {
    float4 im[8];                 // img rows; row r lives in slot r&7
    float4 gprev;                 // grad row L-4 entering body L
    float4 h0, h1;                // hmax rows L-6, L-5
    float4 vmprev;                // vmax row L-6
    float4 n0, n1;                // hmin rows L-8, L-7
};

// LDS-visibility barrier WITHOUT the vmcnt(0) drain __syncthreads adds:
// the global prefetch stays in flight across the barrier.
__device__ __forceinline__ void row_barrier() {
    asm volatile("s_waitcnt lgkmcnt(0)" ::: "memory");
    __builtin_amdgcn_s_barrier();
    asm volatile("" ::: "memory");
}

// One row, LM8 == L & 7 compile-time (y0 % 8 == 0). Round-5 dataflow exactly:
// row L (loaded last body) -> LDS; issue load row L+1; grad L-3; hmax L-4;
// vmax L-5; hmin L-6; out L-7.
template<int LM8, bool RE, bool STORE>
__device__ __forceinline__ void row_body(int L, State& S,
        const float* __restrict__ ip, float* __restrict__ op,
        int lane, int wv, int c0,
        float (*s_img)[SROW], float2 (*eL)[NW], float2 (*eR)[NW]) {
    constexpr int PW = LM8 & 1;        // this body's parity
    constexpr int PR = PW ^ 1;         // previous body's parity
    constexpr int SW = LM8 & 3;        // s_img write slot (row L)
    constexpr int SR = (LM8 + 1) & 3;  // s_img read slot (row L-3)

    // cross-wave edge pairs {grad, vmax} published last body (1 barrier old)
    float2 eRn = (wv > 0)      ? eR[PR][wv - 1] : make_float2(-INFINITY, INFINITY);
    float2 eLn = (wv < NW - 1) ? eL[PR][wv + 1] : make_float2(-INFINITY, INFINITY);

    // row L (in registers since last body) -> LDS ring
    float4 v = S.im[LM8];
    *(float4*)&s_img[SW][c0 + 4] = v;

    // issue load of row L+1 straight into its im slot (slot (L+1)&7 is dead:
    // it held row L-7, last consumed at body L-1)
    {
        float4 nv = f4s(0.f);
        if (!RE || (L + 1) < Hd) nv = *(const float4*)(ip + (size_t)(L + 1) * Wd);
        S.im[(LM8 + 1) & 7] = nv;
    }

    // ---- gradient row L-3 (x-halo via LDS, written 3 barriers ago) ----
    const float* sr = s_img[SR];
    float4 lf = *(const float4*)&sr[c0];       // cols c0-4..c0-1 (zero halo)
    float4 rt = *(const float4*)&sr[c0 + 8];   // cols c0+4..c0+7
    float4 gv = grad_row(S.im[(LM8 + 5) & 7], lf, rt,                     // ce = L-3
                         S.im[(LM8 + 6) & 7], S.im[(LM8 + 4) & 7],        // L-2 - L-4
                         S.im[(LM8 + 7) & 7], S.im[(LM8 + 3) & 7],        // L-1 - L-5
                         v,                    S.im[(LM8 + 2) & 7]);      // L   - L-6

    // ---- hmax row L-4 (gprev = grad L-4; edges 1 barrier old) ----
    float gl = __shfl_up(S.gprev.w, 1, 64);
    if (lane == 0)  gl = eRn.x;
    float gr = __shfl_down(S.gprev.x, 1, 64);
    if (lane == 63) gr = eLn.x;
    float4 hm;
    hm.x = fmaxf(fmaxf(gl,        S.gprev.x), S.gprev.y);
    hm.y = fmaxf(fmaxf(S.gprev.x, S.gprev.y), S.gprev.z);
    hm.z = fmaxf(fmaxf(S.gprev.y, S.gprev.z), S.gprev.w);
    hm.w = fmaxf(fmaxf(S.gprev.z, S.gprev.w), gr);
    if (RE) { if ((unsigned)(L - 4) >= (unsigned)Hd) hm = f4s(-INFINITY); }

    // ---- vmax row L-5 ----
    float4 vm;
    vm.x = fmaxf(fmaxf(S.h0.x, S.h1.x), hm.x);
    vm.y = fmaxf(fmaxf(S.h0.y, S.h1.y), hm.y);
    vm.z = fmaxf(fmaxf(S.h0.z, S.h1.z), hm.z);
    vm.w = fmaxf(fmaxf(S.h0.w, S.h1.w), hm.w);
    if (RE) { if ((unsigned)(L - 5) >= (unsigned)Hd) vm = f4s(INFINITY); }

    // ---- hmin row L-6 (vmprev = vmax L-6; edges 1 barrier old) ----
    float vl  = __shfl_up(S.vmprev.w, 1, 64);
    if (lane == 0)  vl = eRn.y;
    float vr_ = __shfl_down(S.vmprev.x, 1, 64);
    if (lane == 63) vr_ = eLn.y;
    float4 hn;
    hn.x = fminf(fminf(vl,          S.vmprev.x), S.vmprev.y);
    hn.y = fminf(fminf(S.vmprev.x,  S.vmprev.y), S.vmprev.z);
    hn.z = fminf(fminf(S.vmprev.y,  S.vmprev.z), S.vmprev.w);
    hn.w = fminf(fminf(S.vmprev.z,  S.vmprev.w), vr_);

    // ---- out row L-7 ----
    if (STORE) {
        float4 o;
        o.x = fminf(fminf(S.n0.x, S.n1.x), hn.x);
        o.y = fminf(fminf(S.n0.y, S.n1.y), hn.y);
        o.z = fminf(fminf(S.n0.z, S.n1.z), hn.z);
        o.w = fminf(fminf(S.n0.w, S.n1.w), hn.w);
        *(float4*)(op + (size_t)(L - 7) * Wd) = o;
    }

    // ---- ring updates (pure renames under full unroll) ----
    S.h0 = S.h1; S.h1 = hm;
    S.n0 = S.n1; S.n1 = hn;
    S.gprev = gv; S.vmprev = vm;

    // ---- packed edge publishes; consumed next body ----
    if (lane == 0)  eL[PW][wv] = make_float2(gv.x, vm.x);
    if (lane == 63) eR[PW][wv] = make_float2(gv.w, vm.w);

    row_barrier();
}

template<bool RE>
__device__ __forceinline__ void sweep(
        const float* __restrict__ ip, float* __restrict__ op, int y0,
        int tid, int lane, int wv, int c0,
        float (*s_img)[SROW], float2 (*eL)[NW], float2 (*eR)[NW]) {
    // constant zero halo columns (in-loop writes cover only [4, Wd+3])
    if (tid < 32) {
        int r = tid >> 3, j = tid & 7;
        int col = (j < 4) ? j : (Wd + j);
        s_img[r][col] = 0.0f;
    }
    // hygiene init of edge buffers (first-body reads feed only never-stored rows)
    if (tid >= 32 && tid < 32 + 2 * NW) {
        int p = (tid - 32) >> 3, w = (tid - 32) & 7;
        eL[p][w] = make_float2(-INFINITY, INFINITY);
        eR[p][w] = make_float2(-INFINITY, INFINITY);
    }

    State S;
    S.gprev = f4s(0.f);
    S.h0 = S.h1 = f4s(-INFINITY);
    S.vmprev = f4s(INFINITY);
    S.n0 = S.n1 = f4s(INFINITY);

    // ---- prime: rows y0-6..y0-1 -> im slots 2..7; rows y0-3..y0-1 -> LDS 1..3
    #pragma unroll
    for (int r = 0; r < 6; ++r) {
        int row = y0 - 6 + r;
        float4 v = f4s(0.f);
        if (!RE || row >= 0) v = *(const float4*)(ip + (size_t)row * Wd);
        S.im[(r + 2) & 7] = v;
        if (r >= 3) *(float4*)&s_img[(r + 2) & 3][c0 + 4] = v;  // slots 1,2,3
    }
    S.im[0] = *(const float4*)(ip + (size_t)y0 * Wd);  // row y0 (always valid)
    S.im[1] = f4s(0.f);                                 // slot for row y0+1
    __syncthreads();

    // ---- warm-up: 7 bodies, no store ----
    row_body<0, RE, false>(y0 + 0, S, ip, op, lane, wv, c0, s_img, eL, eR);
    row_body<1, RE, false>(y0 + 1, S, ip, op, lane, wv, c0, s_img, eL, eR);
    row_body<2, RE, false>(y0 + 2, S, ip, op, lane, wv, c0, s_img, eL, eR);
    row_body<3, RE, false>(y0 + 3, S, ip, op, lane, wv, c0, s_img, eL, eR);
    row_body<4, RE, false>(y0 + 4, S, ip, op, lane, wv, c0, s_img, eL, eR);
    row_body<5, RE, false>(y0 + 5, S, ip, op, lane, wv, c0, s_img, eL, eR);
    row_body<6, RE, false>(y0 + 6, S, ip, op, lane, wv, c0, s_img, eL, eR);

    // ---- steady: 32 store bodies (rows y0 .. y0+31), all slots compile-time
    #pragma unroll 1
    for (int jj = 0; jj < 4; ++jj) {
        const int Lb = y0 + 7 + jj * 8;   // Lb % 8 == 7
        row_body<7, RE, true>(Lb + 0, S, ip, op, lane, wv, c0, s_img, eL, eR);
        row_body<0, RE, true>(Lb + 1, S, ip, op, lane, wv, c0, s_img, eL, eR);
        row_body<1, RE, true>(Lb + 2, S, ip, op, lane, wv, c0, s_img, eL, eR);
        row_body<2, RE, true>(Lb + 3, S, ip, op, lane, wv, c0, s_img, eL, eR);
        row_body<3, RE, true>(Lb + 4, S, ip, op, lane, wv, c0, s_img, eL, eR);
        row_body<4, RE, true>(Lb + 5, S, ip, op, lane, wv, c0, s_img, eL, eR);
        row_body<5, RE, true>(Lb + 6, S, ip, op, lane, wv, c0, s_img, eL, eR);
        row_body<6, RE, true>(Lb + 7, S, ip, op, lane, wv, c0, s_img, eL, eR);
    }
}

__global__ __launch_bounds__(NT, 8) void gradmap_pipe1_kernel(
        const float* __restrict__ img, float* __restrict__ out) {
    const int plane = blockIdx.y;
    const int y0 = blockIdx.x * CH;
    const int tid = threadIdx.x;
    const int lane = tid & 63;
    const int wv = tid >> 6;
    const int c0 = tid << 2;
    const float* ip = img + (size_t)plane * Hd * Wd + c0;
    float*       op = out + (size_t)plane * Hd * Wd + c0;

    __shared__ float s_img[4][SROW];
    __shared__ float2 s_eL[2][NW], s_eR[2][NW];  // {grad, vmax} edge pairs

    if (blockIdx.x == 0 || blockIdx.x == gridDim.x - 1)
        sweep<true >(ip, op, y0, tid, lane, wv, c0, s_img, s_eL, s_eR);
    else
        sweep<false>(ip, op, y0, tid, lane, wv, c0, s_img, s_eL, s_eR);
}

extern "C" void kernel_launch(void* const* d_in, const int* in_sizes, int n_in,
                              void* d_out, int out_size, void* d_ws, size_t ws_size,
                              hipStream_t stream) {
    const float* img = (const float*)d_in[0];
    float* out = (float*)d_out;
    dim3 grid(Hd / CH, BC);   // 32 x 24 = 768 blocks = 3/CU, balanced
    dim3 block(NT);
    gradmap_pipe1_kernel<<<grid, block, 0, stream>>>(img, out);
}

// Round 10
// 295.298 us; speedup vs baseline: 1.9269x; 1.9269x over previous
//
#include <hip/hip_runtime.h>
#include <math.h>

// img (8, 3, 1024, 2048) fp32 -> same-shape fp32 output.
// Round-5 champion skeleton (1-row bodies, 8 waves, one non-draining barrier
// per row) + fully static unroll, packed float2 edges.
// Round-9 lesson: __launch_bounds__(512,8) pinned VGPR<=64 -> full state spill
// to scratch (VGPR 32, 2.45 GB HBM traffic, 569us). Correct pin for 3 blocks/CU
// with 8-wave blocks is 6 waves/EU -> VGPR cap 84, no spill.
#define Wd 2048
#define Hd 1024
#define BC 24
#define CH 32          // output rows per block chunk (y0 % 8 == 0)
#define NT 512         // 8 waves; lane owns 4 consecutive cols
#define NW 8
#define SROW (Wd + 8)  // LDS img row: col c at index c+4 (zero halo +-4)

__device__ __forceinline__ float4 f4s(float v) { return make_float4(v, v, v, v); }

// Exact-equivalent rewrite of the reference masking (verified r4-r6/r8-r9, absmax 0).
__device__ __forceinline__ float masked_grad1(float g1, float g2, float g3) {
    const float HALF_T     = (float)(0.5 / 1023.0);
    const float GRD_BOTTOM = (float)(1.0 / 1023.0);
    const float GRD_UP     = (float)(4.0 / 1023.0);
    const float THIRD      = (float)(1.0 / 3.0);
    float m  = (g1 + g2 + g3) * THIRD;
    float lo = m - HALF_T;
    float hi = m + HALF_T;
    float a  = fabsf(g1);
    bool keep = (g1 >= lo) & (g1 <= hi) & (a >= GRD_BOTTOM) & (a <= GRD_UP);
    return keep ? g1 : 0.0f;
}

// One gradmap row: ce/lf/rt = x-halo; (a_k, b_k) give y diffs a_k - b_k.
__device__ __forceinline__ float4 grad_row(float4 ce, float4 lf, float4 rt,
        float4 a1, float4 b1, float4 a2, float4 b2, float4 a3, float4 b3) {
    const float K = 255.75f;  // 1023/4 exact
    float gx0 = masked_grad1(ce.y - lf.w, ce.z - lf.z, ce.w - lf.y);
    float gx1 = masked_grad1(ce.z - ce.x, ce.w - lf.w, rt.x - lf.z);
    float gx2 = masked_grad1(ce.w - ce.y, rt.x - ce.x, rt.y - lf.w);
    float gx3 = masked_grad1(rt.x - ce.z, rt.y - ce.y, rt.z - ce.x);
    float gy0 = masked_grad1(a1.x - b1.x, a2.x - b2.x, a3.x - b3.x);
    float gy1 = masked_grad1(a1.y - b1.y, a2.y - b2.y, a3.y - b3.y);
    float gy2 = masked_grad1(a1.z - b1.z, a2.z - b2.z, a3.z - b3.z);
    float gy3 = masked_grad1(a1.w - b1.w, a2.w - b2.w, a3.w - b3.w);
    float4 g;
    g.x = fmaxf(fabsf(gx0), fabsf(gy0)) * K;
    g.y = fmaxf(fabsf(gx1), fabsf(gy1)) * K;
    g.z = fmaxf(fabsf(gx2), fabsf(gy2)) * K;
    g.w = fmaxf(fabsf(gx3), fabsf(gy3)) * K;
    return g;
}

struct State {
    float4 im[8];                 // img rows; row r lives in slot r&7
    float4 gprev;                 // grad row L-4 entering body L
    float4 h0, h1;                // hmax rows L-6, L-5
    float4 vmprev;                // vmax row L-6
    float4 n0, n1;                // hmin rows L-8, L-7
};

// LDS-visibility barrier WITHOUT the vmcnt(0) drain __syncthreads adds:
// the global prefetch stays in flight across the barrier.
__device__ __forceinline__ void row_barrier() {
    asm volatile("s_waitcnt lgkmcnt(0)" ::: "memory");
    __builtin_amdgcn_s_barrier();
    asm volatile("" ::: "memory");
}

// One row, LM8 == L & 7 compile-time (y0 % 8 == 0). Round-5 dataflow exactly:
// row L (loaded last body) -> LDS; issue load row L+1; grad L-3; hmax L-4;
// vmax L-5; hmin L-6; out L-7.
template<int LM8, bool RE, bool STORE>
__device__ __forceinline__ void row_body(int L, State& S,
        const float* __restrict__ ip, float* __restrict__ op,
        int lane, int wv, int c0,
        float (*s_img)[SROW], float2 (*eL)[NW], float2 (*eR)[NW]) {
    constexpr int PW = LM8 & 1;        // this body's parity
    constexpr int PR = PW ^ 1;         // previous body's parity
    constexpr int SW = LM8 & 3;        // s_img write slot (row L)
    constexpr int SR = (LM8 + 1) & 3;  // s_img read slot (row L-3)

    // cross-wave edge pairs {grad, vmax} published last body (1 barrier old)
    float2 eRn = (wv > 0)      ? eR[PR][wv - 1] : make_float2(-INFINITY, INFINITY);
    float2 eLn = (wv < NW - 1) ? eL[PR][wv + 1] : make_float2(-INFINITY, INFINITY);

    // row L (in registers since last body) -> LDS ring
    float4 v = S.im[LM8];
    *(float4*)&s_img[SW][c0 + 4] = v;

    // issue load of row L+1 straight into its im slot (slot (L+1)&7 is dead:
    // it held row L-7, last consumed at body L-1)
    {
        float4 nv = f4s(0.f);
        if (!RE || (L + 1) < Hd) nv = *(const float4*)(ip + (size_t)(L + 1) * Wd);
        S.im[(LM8 + 1) & 7] = nv;
    }

    // ---- gradient row L-3 (x-halo via LDS, written 3 barriers ago) ----
    const float* sr = s_img[SR];
    float4 lf = *(const float4*)&sr[c0];       // cols c0-4..c0-1 (zero halo)
    float4 rt = *(const float4*)&sr[c0 + 8];   // cols c0+4..c0+7
    float4 gv = grad_row(S.im[(LM8 + 5) & 7], lf, rt,                     // ce = L-3
                         S.im[(LM8 + 6) & 7], S.im[(LM8 + 4) & 7],        // L-2 - L-4
                         S.im[(LM8 + 7) & 7], S.im[(LM8 + 3) & 7],        // L-1 - L-5
                         v,                    S.im[(LM8 + 2) & 7]);      // L   - L-6

    // ---- hmax row L-4 (gprev = grad L-4; edges 1 barrier old) ----
    float gl = __shfl_up(S.gprev.w, 1, 64);
    if (lane == 0)  gl = eRn.x;
    float gr = __shfl_down(S.gprev.x, 1, 64);
    if (lane == 63) gr = eLn.x;
    float4 hm;
    hm.x = fmaxf(fmaxf(gl,        S.gprev.x), S.gprev.y);
    hm.y = fmaxf(fmaxf(S.gprev.x, S.gprev.y), S.gprev.z);
    hm.z = fmaxf(fmaxf(S.gprev.y, S.gprev.z), S.gprev.w);
    hm.w = fmaxf(fmaxf(S.gprev.z, S.gprev.w), gr);
    if (RE) { if ((unsigned)(L - 4) >= (unsigned)Hd) hm = f4s(-INFINITY); }

    // ---- vmax row L-5 ----
    float4 vm;
    vm.x = fmaxf(fmaxf(S.h0.x, S.h1.x), hm.x);
    vm.y = fmaxf(fmaxf(S.h0.y, S.h1.y), hm.y);
    vm.z = fmaxf(fmaxf(S.h0.z, S.h1.z), hm.z);
    vm.w = fmaxf(fmaxf(S.h0.w, S.h1.w), hm.w);
    if (RE) { if ((unsigned)(L - 5) >= (unsigned)Hd) vm = f4s(INFINITY); }

    // ---- hmin row L-6 (vmprev = vmax L-6; edges 1 barrier old) ----
    float vl  = __shfl_up(S.vmprev.w, 1, 64);
    if (lane == 0)  vl = eRn.y;
    float vr_ = __shfl_down(S.vmprev.x, 1, 64);
    if (lane == 63) vr_ = eLn.y;
    float4 hn;
    hn.x = fminf(fminf(vl,          S.vmprev.x), S.vmprev.y);
    hn.y = fminf(fminf(S.vmprev.x,  S.vmprev.y), S.vmprev.z);
    hn.z = fminf(fminf(S.vmprev.y,  S.vmprev.z), S.vmprev.w);
    hn.w = fminf(fminf(S.vmprev.z,  S.vmprev.w), vr_);

    // ---- out row L-7 ----
    if (STORE) {
        float4 o;
        o.x = fminf(fminf(S.n0.x, S.n1.x), hn.x);
        o.y = fminf(fminf(S.n0.y, S.n1.y), hn.y);
        o.z = fminf(fminf(S.n0.z, S.n1.z), hn.z);
        o.w = fminf(fminf(S.n0.w, S.n1.w), hn.w);
        *(float4*)(op + (size_t)(L - 7) * Wd) = o;
    }

    // ---- ring updates (pure renames under full unroll) ----
    S.h0 = S.h1; S.h1 = hm;
    S.n0 = S.n1; S.n1 = hn;
    S.gprev = gv; S.vmprev = vm;

    // ---- packed edge publishes; consumed next body ----
    if (lane == 0)  eL[PW][wv] = make_float2(gv.x, vm.x);
    if (lane == 63) eR[PW][wv] = make_float2(gv.w, vm.w);

    row_barrier();
}

template<bool RE>
__device__ __forceinline__ void sweep(
        const float* __restrict__ ip, float* __restrict__ op, int y0,
        int tid, int lane, int wv, int c0,
        float (*s_img)[SROW], float2 (*eL)[NW], float2 (*eR)[NW]) {
    // constant zero halo columns (in-loop writes cover only [4, Wd+3])
    if (tid < 32) {
        int r = tid >> 3, j = tid & 7;
        int col = (j < 4) ? j : (Wd + j);
        s_img[r][col] = 0.0f;
    }
    // hygiene init of edge buffers (first-body reads feed only never-stored rows)
    if (tid >= 32 && tid < 32 + 2 * NW) {
        int p = (tid - 32) >> 3, w = (tid - 32) & 7;
        eL[p][w] = make_float2(-INFINITY, INFINITY);
        eR[p][w] = make_float2(-INFINITY, INFINITY);
    }

    State S;
    S.gprev = f4s(0.f);
    S.h0 = S.h1 = f4s(-INFINITY);
    S.vmprev = f4s(INFINITY);
    S.n0 = S.n1 = f4s(INFINITY);

    // ---- prime: rows y0-6..y0-1 -> im slots 2..7; rows y0-3..y0-1 -> LDS 1..3
    #pragma unroll
    for (int r = 0; r < 6; ++r) {
        int row = y0 - 6 + r;
        float4 v = f4s(0.f);
        if (!RE || row >= 0) v = *(const float4*)(ip + (size_t)row * Wd);
        S.im[(r + 2) & 7] = v;
        if (r >= 3) *(float4*)&s_img[(r + 2) & 3][c0 + 4] = v;  // slots 1,2,3
    }
    S.im[0] = *(const float4*)(ip + (size_t)y0 * Wd);  // row y0 (always valid)
    S.im[1] = f4s(0.f);                                 // slot for row y0+1
    __syncthreads();

    // ---- warm-up: 7 bodies, no store ----
    row_body<0, RE, false>(y0 + 0, S, ip, op, lane, wv, c0, s_img, eL, eR);
    row_body<1, RE, false>(y0 + 1, S, ip, op, lane, wv, c0, s_img, eL, eR);
    row_body<2, RE, false>(y0 + 2, S, ip, op, lane, wv, c0, s_img, eL, eR);
    row_body<3, RE, false>(y0 + 3, S, ip, op, lane, wv, c0, s_img, eL, eR);
    row_body<4, RE, false>(y0 + 4, S, ip, op, lane, wv, c0, s_img, eL, eR);
    row_body<5, RE, false>(y0 + 5, S, ip, op, lane, wv, c0, s_img, eL, eR);
    row_body<6, RE, false>(y0 + 6, S, ip, op, lane, wv, c0, s_img, eL, eR);

    // ---- steady: 32 store bodies (rows y0 .. y0+31), all slots compile-time
    #pragma unroll 1
    for (int jj = 0; jj < 4; ++jj) {
        const int Lb = y0 + 7 + jj * 8;   // Lb % 8 == 7
        row_body<7, RE, true>(Lb + 0, S, ip, op, lane, wv, c0, s_img, eL, eR);
        row_body<0, RE, true>(Lb + 1, S, ip, op, lane, wv, c0, s_img, eL, eR);
        row_body<1, RE, true>(Lb + 2, S, ip, op, lane, wv, c0, s_img, eL, eR);
        row_body<2, RE, true>(Lb + 3, S, ip, op, lane, wv, c0, s_img, eL, eR);
        row_body<3, RE, true>(Lb + 4, S, ip, op, lane, wv, c0, s_img, eL, eR);
        row_body<4, RE, true>(Lb + 5, S, ip, op, lane, wv, c0, s_img, eL, eR);
        row_body<5, RE, true>(Lb + 6, S, ip, op, lane, wv, c0, s_img, eL, eR);
        row_body<6, RE, true>(Lb + 7, S, ip, op, lane, wv, c0, s_img, eL, eR);
    }
}

// 6 waves/EU min => VGPR cap 84: guarantees 3 resident 8-wave blocks/CU
// without starving the allocator (round-9 spill lesson).
__global__ __launch_bounds__(NT, 6) void gradmap_pipe1b_kernel(
        const float* __restrict__ img, float* __restrict__ out) {
    const int plane = blockIdx.y;
    const int y0 = blockIdx.x * CH;
    const int tid = threadIdx.x;
    const int lane = tid & 63;
    const int wv = tid >> 6;
    const int c0 = tid << 2;
    const float* ip = img + (size_t)plane * Hd * Wd + c0;
    float*       op = out + (size_t)plane * Hd * Wd + c0;

    __shared__ float s_img[4][SROW];
    __shared__ float2 s_eL[2][NW], s_eR[2][NW];  // {grad, vmax} edge pairs

    if (blockIdx.x == 0 || blockIdx.x == gridDim.x - 1)
        sweep<true >(ip, op, y0, tid, lane, wv, c0, s_img, s_eL, s_eR);
    else
        sweep<false>(ip, op, y0, tid, lane, wv, c0, s_img, s_eL, s_eR);
}

extern "C" void kernel_launch(void* const* d_in, const int* in_sizes, int n_in,
                              void* d_out, int out_size, void* d_ws, size_t ws_size,
                              hipStream_t stream) {
    const float* img = (const float*)d_in[0];
    float* out = (float*)d_out;
    dim3 grid(Hd / CH, BC);   // 32 x 24 = 768 blocks = 3/CU, balanced
    dim3 block(NT);
    gradmap_pipe1b_kernel<<<grid, block, 0, stream>>>(img, out);
}

// Round 11
// 102.555 us; speedup vs baseline: 5.5482x; 2.8794x over previous
//
#include <hip/hip_runtime.h>
#include <math.h>

// img (8, 3, 1024, 2048) fp32 -> same-shape fp32 output.
// Round-5 champion skeleton (1-row bodies, 8 waves, one non-draining barrier
// per row) + fully static unroll, packed float2 edges.
// Launch-bounds decode (r9/r10 data): hipcc's 2nd arg = min BLOCKS per CU
// (CUDA semantics), NOT waves/EU: arg8->VGPR32, arg6->VGPR40 (=512/(8*arg/4)).
// So 3 blocks/CU x 8 waves = 6 waves/SIMD -> VGPR cap 84: the intended pin.
#define Wd 2048
#define Hd 1024
#define BC 24
#define CH 32          // output rows per block chunk (y0 % 8 == 0)
#define NT 512         // 8 waves; lane owns 4 consecutive cols
#define NW 8
#define SROW (Wd + 8)  // LDS img row: col c at index c+4 (zero halo +-4)

__device__ __forceinline__ float4 f4s(float v) { return make_float4(v, v, v, v); }

// Exact-equivalent rewrite of the reference masking (verified r4-r10, absmax 0).
__device__ __forceinline__ float masked_grad1(float g1, float g2, float g3) {
    const float HALF_T     = (float)(0.5 / 1023.0);
    const float GRD_BOTTOM = (float)(1.0 / 1023.0);
    const float GRD_UP     = (float)(4.0 / 1023.0);
    const float THIRD      = (float)(1.0 / 3.0);
    float m  = (g1 + g2 + g3) * THIRD;
    float lo = m - HALF_T;
    float hi = m + HALF_T;
    float a  = fabsf(g1);
    bool keep = (g1 >= lo) & (g1 <= hi) & (a >= GRD_BOTTOM) & (a <= GRD_UP);
    return keep ? g1 : 0.0f;
}

// One gradmap row: ce/lf/rt = x-halo; (a_k, b_k) give y diffs a_k - b_k.
__device__ __forceinline__ float4 grad_row(float4 ce, float4 lf, float4 rt,
        float4 a1, float4 b1, float4 a2, float4 b2, float4 a3, float4 b3) {
    const float K = 255.75f;  // 1023/4 exact
    float gx0 = masked_grad1(ce.y - lf.w, ce.z - lf.z, ce.w - lf.y);
    float gx1 = masked_grad1(ce.z - ce.x, ce.w - lf.w, rt.x - lf.z);
    float gx2 = masked_grad1(ce.w - ce.y, rt.x - ce.x, rt.y - lf.w);
    float gx3 = masked_grad1(rt.x - ce.z, rt.y - ce.y, rt.z - ce.x);
    float gy0 = masked_grad1(a1.x - b1.x, a2.x - b2.x, a3.x - b3.x);
    float gy1 = masked_grad1(a1.y - b1.y, a2.y - b2.y, a3.y - b3.y);
    float gy2 = masked_grad1(a1.z - b1.z, a2.z - b2.z, a3.z - b3.z);
    float gy3 = masked_grad1(a1.w - b1.w, a2.w - b2.w, a3.w - b3.w);
    float4 g;
    g.x = fmaxf(fabsf(gx0), fabsf(gy0)) * K;
    g.y = fmaxf(fabsf(gx1), fabsf(gy1)) * K;
    g.z = fmaxf(fabsf(gx2), fabsf(gy2)) * K;
    g.w = fmaxf(fabsf(gx3), fabsf(gy3)) * K;
    return g;
}

struct State {
    float4 im[8];                 // img rows; row r lives in slot r&7
    float4 gprev;                 // grad row L-4 entering body L
    float4 h0, h1;                // hmax rows L-6, L-5
    float4 vmprev;                // vmax row L-6
    float4 n0, n1;                // hmin rows L-8, L-7
};

// LDS-visibility barrier WITHOUT the vmcnt(0) drain __syncthreads adds:
// the global prefetch stays in flight across the barrier.
__device__ __forceinline__ void row_barrier() {
    asm volatile("s_waitcnt lgkmcnt(0)" ::: "memory");
    __builtin_amdgcn_s_barrier();
    asm volatile("" ::: "memory");
}

// One row, LM8 == L & 7 compile-time (y0 % 8 == 0). Round-5 dataflow exactly:
// row L (loaded last body) -> LDS; issue load row L+1; grad L-3; hmax L-4;
// vmax L-5; hmin L-6; out L-7.
template<int LM8, bool RE, bool STORE>
__device__ __forceinline__ void row_body(int L, State& S,
        const float* __restrict__ ip, float* __restrict__ op,
        int lane, int wv, int c0,
        float (*s_img)[SROW], float2 (*eL)[NW], float2 (*eR)[NW]) {
    constexpr int PW = LM8 & 1;        // this body's parity
    constexpr int PR = PW ^ 1;         // previous body's parity
    constexpr int SW = LM8 & 3;        // s_img write slot (row L)
    constexpr int SR = (LM8 + 1) & 3;  // s_img read slot (row L-3)

    // cross-wave edge pairs {grad, vmax} published last body (1 barrier old)
    float2 eRn = (wv > 0)      ? eR[PR][wv - 1] : make_float2(-INFINITY, INFINITY);
    float2 eLn = (wv < NW - 1) ? eL[PR][wv + 1] : make_float2(-INFINITY, INFINITY);

    // row L (in registers since last body) -> LDS ring
    float4 v = S.im[LM8];
    *(float4*)&s_img[SW][c0 + 4] = v;

    // issue load of row L+1 straight into its im slot (slot (L+1)&7 is dead:
    // it held row L-7, last consumed at body L-1)
    {
        float4 nv = f4s(0.f);
        if (!RE || (L + 1) < Hd) nv = *(const float4*)(ip + (size_t)(L + 1) * Wd);
        S.im[(LM8 + 1) & 7] = nv;
    }

    // ---- gradient row L-3 (x-halo via LDS, written 3 barriers ago) ----
    const float* sr = s_img[SR];
    float4 lf = *(const float4*)&sr[c0];       // cols c0-4..c0-1 (zero halo)
    float4 rt = *(const float4*)&sr[c0 + 8];   // cols c0+4..c0+7
    float4 gv = grad_row(S.im[(LM8 + 5) & 7], lf, rt,                     // ce = L-3
                         S.im[(LM8 + 6) & 7], S.im[(LM8 + 4) & 7],        // L-2 - L-4
                         S.im[(LM8 + 7) & 7], S.im[(LM8 + 3) & 7],        // L-1 - L-5
                         v,                    S.im[(LM8 + 2) & 7]);      // L   - L-6

    // ---- hmax row L-4 (gprev = grad L-4; edges 1 barrier old) ----
    float gl = __shfl_up(S.gprev.w, 1, 64);
    if (lane == 0)  gl = eRn.x;
    float gr = __shfl_down(S.gprev.x, 1, 64);
    if (lane == 63) gr = eLn.x;
    float4 hm;
    hm.x = fmaxf(fmaxf(gl,        S.gprev.x), S.gprev.y);
    hm.y = fmaxf(fmaxf(S.gprev.x, S.gprev.y), S.gprev.z);
    hm.z = fmaxf(fmaxf(S.gprev.y, S.gprev.z), S.gprev.w);
    hm.w = fmaxf(fmaxf(S.gprev.z, S.gprev.w), gr);
    if (RE) { if ((unsigned)(L - 4) >= (unsigned)Hd) hm = f4s(-INFINITY); }

    // ---- vmax row L-5 ----
    float4 vm;
    vm.x = fmaxf(fmaxf(S.h0.x, S.h1.x), hm.x);
    vm.y = fmaxf(fmaxf(S.h0.y, S.h1.y), hm.y);
    vm.z = fmaxf(fmaxf(S.h0.z, S.h1.z), hm.z);
    vm.w = fmaxf(fmaxf(S.h0.w, S.h1.w), hm.w);
    if (RE) { if ((unsigned)(L - 5) >= (unsigned)Hd) vm = f4s(INFINITY); }

    // ---- hmin row L-6 (vmprev = vmax L-6; edges 1 barrier old) ----
    float vl  = __shfl_up(S.vmprev.w, 1, 64);
    if (lane == 0)  vl = eRn.y;
    float vr_ = __shfl_down(S.vmprev.x, 1, 64);
    if (lane == 63) vr_ = eLn.y;
    float4 hn;
    hn.x = fminf(fminf(vl,          S.vmprev.x), S.vmprev.y);
    hn.y = fminf(fminf(S.vmprev.x,  S.vmprev.y), S.vmprev.z);
    hn.z = fminf(fminf(S.vmprev.y,  S.vmprev.z), S.vmprev.w);
    hn.w = fminf(fminf(S.vmprev.z,  S.vmprev.w), vr_);

    // ---- out row L-7 ----
    if (STORE) {
        float4 o;
        o.x = fminf(fminf(S.n0.x, S.n1.x), hn.x);
        o.y = fminf(fminf(S.n0.y, S.n1.y), hn.y);
        o.z = fminf(fminf(S.n0.z, S.n1.z), hn.z);
        o.w = fminf(fminf(S.n0.w, S.n1.w), hn.w);
        *(float4*)(op + (size_t)(L - 7) * Wd) = o;
    }

    // ---- ring updates (pure renames under full unroll) ----
    S.h0 = S.h1; S.h1 = hm;
    S.n0 = S.n1; S.n1 = hn;
    S.gprev = gv; S.vmprev = vm;

    // ---- packed edge publishes; consumed next body ----
    if (lane == 0)  eL[PW][wv] = make_float2(gv.x, vm.x);
    if (lane == 63) eR[PW][wv] = make_float2(gv.w, vm.w);

    row_barrier();
}

template<bool RE>
__device__ __forceinline__ void sweep(
        const float* __restrict__ ip, float* __restrict__ op, int y0,
        int tid, int lane, int wv, int c0,
        float (*s_img)[SROW], float2 (*eL)[NW], float2 (*eR)[NW]) {
    // constant zero halo columns (in-loop writes cover only [4, Wd+3])
    if (tid < 32) {
        int r = tid >> 3, j = tid & 7;
        int col = (j < 4) ? j : (Wd + j);
        s_img[r][col] = 0.0f;
    }
    // hygiene init of edge buffers (first-body reads feed only never-stored rows)
    if (tid >= 32 && tid < 32 + 2 * NW) {
        int p = (tid - 32) >> 3, w = (tid - 32) & 7;
        eL[p][w] = make_float2(-INFINITY, INFINITY);
        eR[p][w] = make_float2(-INFINITY, INFINITY);
    }

    State S;
    S.gprev = f4s(0.f);
    S.h0 = S.h1 = f4s(-INFINITY);
    S.vmprev = f4s(INFINITY);
    S.n0 = S.n1 = f4s(INFINITY);

    // ---- prime: rows y0-6..y0-1 -> im slots 2..7; rows y0-3..y0-1 -> LDS 1..3
    #pragma unroll
    for (int r = 0; r < 6; ++r) {
        int row = y0 - 6 + r;
        float4 v = f4s(0.f);
        if (!RE || row >= 0) v = *(const float4*)(ip + (size_t)row * Wd);
        S.im[(r + 2) & 7] = v;
        if (r >= 3) *(float4*)&s_img[(r + 2) & 3][c0 + 4] = v;  // slots 1,2,3
    }
    S.im[0] = *(const float4*)(ip + (size_t)y0 * Wd);  // row y0 (always valid)
    S.im[1] = f4s(0.f);                                 // slot for row y0+1
    __syncthreads();

    // ---- warm-up: 7 bodies, no store ----
    row_body<0, RE, false>(y0 + 0, S, ip, op, lane, wv, c0, s_img, eL, eR);
    row_body<1, RE, false>(y0 + 1, S, ip, op, lane, wv, c0, s_img, eL, eR);
    row_body<2, RE, false>(y0 + 2, S, ip, op, lane, wv, c0, s_img, eL, eR);
    row_body<3, RE, false>(y0 + 3, S, ip, op, lane, wv, c0, s_img, eL, eR);
    row_body<4, RE, false>(y0 + 4, S, ip, op, lane, wv, c0, s_img, eL, eR);
    row_body<5, RE, false>(y0 + 5, S, ip, op, lane, wv, c0, s_img, eL, eR);
    row_body<6, RE, false>(y0 + 6, S, ip, op, lane, wv, c0, s_img, eL, eR);

    // ---- steady: 32 store bodies (rows y0 .. y0+31), all slots compile-time
    #pragma unroll 1
    for (int jj = 0; jj < 4; ++jj) {
        const int Lb = y0 + 7 + jj * 8;   // Lb % 8 == 7
        row_body<7, RE, true>(Lb + 0, S, ip, op, lane, wv, c0, s_img, eL, eR);
        row_body<0, RE, true>(Lb + 1, S, ip, op, lane, wv, c0, s_img, eL, eR);
        row_body<1, RE, true>(Lb + 2, S, ip, op, lane, wv, c0, s_img, eL, eR);
        row_body<2, RE, true>(Lb + 3, S, ip, op, lane, wv, c0, s_img, eL, eR);
        row_body<3, RE, true>(Lb + 4, S, ip, op, lane, wv, c0, s_img, eL, eR);
        row_body<4, RE, true>(Lb + 5, S, ip, op, lane, wv, c0, s_img, eL, eR);
        row_body<5, RE, true>(Lb + 6, S, ip, op, lane, wv, c0, s_img, eL, eR);
        row_body<6, RE, true>(Lb + 7, S, ip, op, lane, wv, c0, s_img, eL, eR);
    }
}

// 2nd arg = min BLOCKS per CU on this toolchain (r9/r10 decode):
// 3 blocks x 8 waves = 6 waves/SIMD -> VGPR cap 84. No spill expected.
__global__ __launch_bounds__(NT, 3) void gradmap_pipe1c_kernel(
        const float* __restrict__ img, float* __restrict__ out) {
    const int plane = blockIdx.y;
    const int y0 = blockIdx.x * CH;
    const int tid = threadIdx.x;
    const int lane = tid & 63;
    const int wv = tid >> 6;
    const int c0 = tid << 2;
    const float* ip = img + (size_t)plane * Hd * Wd + c0;
    float*       op = out + (size_t)plane * Hd * Wd + c0;

    __shared__ float s_img[4][SROW];
    __shared__ float2 s_eL[2][NW], s_eR[2][NW];  // {grad, vmax} edge pairs

    if (blockIdx.x == 0 || blockIdx.x == gridDim.x - 1)
        sweep<true >(ip, op, y0, tid, lane, wv, c0, s_img, s_eL, s_eR);
    else
        sweep<false>(ip, op, y0, tid, lane, wv, c0, s_img, s_eL, s_eR);
}

extern "C" void kernel_launch(void* const* d_in, const int* in_sizes, int n_in,
                              void* d_out, int out_size, void* d_ws, size_t ws_size,
                              hipStream_t stream) {
    const float* img = (const float*)d_in[0];
    float* out = (float*)d_out;
    dim3 grid(Hd / CH, BC);   // 32 x 24 = 768 blocks = 3/CU, balanced
    dim3 block(NT);
    gradmap_pipe1c_kernel<<<grid, block, 0, stream>>>(img, out);
}

// Round 12
// 102.398 us; speedup vs baseline: 5.5567x; 1.0015x over previous
//
#include <hip/hip_runtime.h>
#include <math.h>

// img (8, 3, 1024, 2048) fp32 -> same-shape fp32 output.
// Round-11 skeleton (1-row bodies, 8 waves, non-draining barrier per row,
// static unroll, packed float2 edges) with:
//   * CH=16 -> grid 1536 blocks -> 4 co-resident blocks/CU (32 waves) for TLP
//   * __launch_bounds__(512,4): toolchain 2nd arg = blocks/CU (r9/r10 decode),
//     4 blocks -> VGPR cap 64 (natural 60 fits; 64 is the occupancy cliff, m69)
//   * K-scale deferred to the store (exact: monotone scale commutes w/ max/min)
#define Wd 2048
#define Hd 1024
#define BC 24
#define CH 16          // output rows per block chunk (y0 % 8 == 0)
#define NT 512         // 8 waves; lane owns 4 consecutive cols
#define NW 8
#define SROW (Wd + 8)  // LDS img row: col c at index c+4 (zero halo +-4)

__device__ __forceinline__ float4 f4s(float v) { return make_float4(v, v, v, v); }

// Exact-equivalent rewrite of the reference masking (verified r4-r11, absmax 0).
__device__ __forceinline__ float masked_grad1(float g1, float g2, float g3) {
    const float HALF_T     = (float)(0.5 / 1023.0);
    const float GRD_BOTTOM = (float)(1.0 / 1023.0);
    const float GRD_UP     = (float)(4.0 / 1023.0);
    const float THIRD      = (float)(1.0 / 3.0);
    float m  = (g1 + g2 + g3) * THIRD;
    float lo = m - HALF_T;
    float hi = m + HALF_T;
    float a  = fabsf(g1);
    bool keep = (g1 >= lo) & (g1 <= hi) & (a >= GRD_BOTTOM) & (a <= GRD_UP);
    return keep ? g1 : 0.0f;
}

// One UNSCALED gradmap row (K applied at store; exact since x<=y <=> Kx<=Ky
// and rounding is monotone, so round-after-scale commutes with max/min).
__device__ __forceinline__ float4 grad_row(float4 ce, float4 lf, float4 rt,
        float4 a1, float4 b1, float4 a2, float4 b2, float4 a3, float4 b3) {
    float gx0 = masked_grad1(ce.y - lf.w, ce.z - lf.z, ce.w - lf.y);
    float gx1 = masked_grad1(ce.z - ce.x, ce.w - lf.w, rt.x - lf.z);
    float gx2 = masked_grad1(ce.w - ce.y, rt.x - ce.x, rt.y - lf.w);
    float gx3 = masked_grad1(rt.x - ce.z, rt.y - ce.y, rt.z - ce.x);
    float gy0 = masked_grad1(a1.x - b1.x, a2.x - b2.x, a3.x - b3.x);
    float gy1 = masked_grad1(a1.y - b1.y, a2.y - b2.y, a3.y - b3.y);
    float gy2 = masked_grad1(a1.z - b1.z, a2.z - b2.z, a3.z - b3.z);
    float gy3 = masked_grad1(a1.w - b1.w, a2.w - b2.w, a3.w - b3.w);
    float4 g;
    g.x = fmaxf(fabsf(gx0), fabsf(gy0));
    g.y = fmaxf(fabsf(gx1), fabsf(gy1));
    g.z = fmaxf(fabsf(gx2), fabsf(gy2));
    g.w = fmaxf(fabsf(gx3), fabsf(gy3));
    return g;
}

struct State {
    float4 im[8];                 // img rows; row r lives in slot r&7
    float4 gprev;                 // grad row L-4 entering body L
    float4 h0, h1;                // hmax rows L-6, L-5
    float4 vmprev;                // vmax row L-6
    float4 n0, n1;                // hmin rows L-8, L-7
};

// LDS-visibility barrier WITHOUT the vmcnt(0) drain __syncthreads adds:
// the global prefetch stays in flight across the barrier.
__device__ __forceinline__ void row_barrier() {
    asm volatile("s_waitcnt lgkmcnt(0)" ::: "memory");
    __builtin_amdgcn_s_barrier();
    asm volatile("" ::: "memory");
}

// One row, LM8 == L & 7 compile-time (y0 % 8 == 0). Round-5 dataflow exactly:
// row L (loaded last body) -> LDS; issue load row L+1; grad L-3; hmax L-4;
// vmax L-5; hmin L-6; out L-7.
template<int LM8, bool RE, bool STORE>
__device__ __forceinline__ void row_body(int L, State& S,
        const float* __restrict__ ip, float* __restrict__ op,
        int lane, int wv, int c0,
        float (*s_img)[SROW], float2 (*eL)[NW], float2 (*eR)[NW]) {
    constexpr int PW = LM8 & 1;        // this body's parity
    constexpr int PR = PW ^ 1;         // previous body's parity
    constexpr int SW = LM8 & 3;        // s_img write slot (row L)
    constexpr int SR = (LM8 + 1) & 3;  // s_img read slot (row L-3)

    // cross-wave edge pairs {grad, vmax} published last body (1 barrier old)
    float2 eRn = (wv > 0)      ? eR[PR][wv - 1] : make_float2(-INFINITY, INFINITY);
    float2 eLn = (wv < NW - 1) ? eL[PR][wv + 1] : make_float2(-INFINITY, INFINITY);

    // row L (in registers since last body) -> LDS ring
    float4 v = S.im[LM8];
    *(float4*)&s_img[SW][c0 + 4] = v;

    // issue load of row L+1 straight into its im slot (slot (L+1)&7 is dead:
    // it held row L-7, last consumed at body L-1)
    {
        float4 nv = f4s(0.f);
        if (!RE || (L + 1) < Hd) nv = *(const float4*)(ip + (size_t)(L + 1) * Wd);
        S.im[(LM8 + 1) & 7] = nv;
    }

    // ---- gradient row L-3 (x-halo via LDS, written 3 barriers ago) ----
    const float* sr = s_img[SR];
    float4 lf = *(const float4*)&sr[c0];       // cols c0-4..c0-1 (zero halo)
    float4 rt = *(const float4*)&sr[c0 + 8];   // cols c0+4..c0+7
    float4 gv = grad_row(S.im[(LM8 + 5) & 7], lf, rt,                     // ce = L-3
                         S.im[(LM8 + 6) & 7], S.im[(LM8 + 4) & 7],        // L-2 - L-4
                         S.im[(LM8 + 7) & 7], S.im[(LM8 + 3) & 7],        // L-1 - L-5
                         v,                    S.im[(LM8 + 2) & 7]);      // L   - L-6

    // ---- hmax row L-4 (gprev = grad L-4; edges 1 barrier old) ----
    float gl = __shfl_up(S.gprev.w, 1, 64);
    if (lane == 0)  gl = eRn.x;
    float gr = __shfl_down(S.gprev.x, 1, 64);
    if (lane == 63) gr = eLn.x;
    float4 hm;
    hm.x = fmaxf(fmaxf(gl,        S.gprev.x), S.gprev.y);
    hm.y = fmaxf(fmaxf(S.gprev.x, S.gprev.y), S.gprev.z);
    hm.z = fmaxf(fmaxf(S.gprev.y, S.gprev.z), S.gprev.w);
    hm.w = fmaxf(fmaxf(S.gprev.z, S.gprev.w), gr);
    if (RE) { if ((unsigned)(L - 4) >= (unsigned)Hd) hm = f4s(-INFINITY); }

    // ---- vmax row L-5 ----
    float4 vm;
    vm.x = fmaxf(fmaxf(S.h0.x, S.h1.x), hm.x);
    vm.y = fmaxf(fmaxf(S.h0.y, S.h1.y), hm.y);
    vm.z = fmaxf(fmaxf(S.h0.z, S.h1.z), hm.z);
    vm.w = fmaxf(fmaxf(S.h0.w, S.h1.w), hm.w);
    if (RE) { if ((unsigned)(L - 5) >= (unsigned)Hd) vm = f4s(INFINITY); }

    // ---- hmin row L-6 (vmprev = vmax L-6; edges 1 barrier old) ----
    float vl  = __shfl_up(S.vmprev.w, 1, 64);
    if (lane == 0)  vl = eRn.y;
    float vr_ = __shfl_down(S.vmprev.x, 1, 64);
    if (lane == 63) vr_ = eLn.y;
    float4 hn;
    hn.x = fminf(fminf(vl,          S.vmprev.x), S.vmprev.y);
    hn.y = fminf(fminf(S.vmprev.x,  S.vmprev.y), S.vmprev.z);
    hn.z = fminf(fminf(S.vmprev.y,  S.vmprev.z), S.vmprev.w);
    hn.w = fminf(fminf(S.vmprev.z,  S.vmprev.w), vr_);

    // ---- out row L-7 (apply the deferred K scale here) ----
    if (STORE) {
        const float K = 255.75f;  // 1023/4 exact
        float4 o;
        o.x = fminf(fminf(S.n0.x, S.n1.x), hn.x) * K;
        o.y = fminf(fminf(S.n0.y, S.n1.y), hn.y) * K;
        o.z = fminf(fminf(S.n0.z, S.n1.z), hn.z) * K;
        o.w = fminf(fminf(S.n0.w, S.n1.w), hn.w) * K;
        *(float4*)(op + (size_t)(L - 7) * Wd) = o;
    }

    // ---- ring updates (pure renames under full unroll) ----
    S.h0 = S.h1; S.h1 = hm;
    S.n0 = S.n1; S.n1 = hn;
    S.gprev = gv; S.vmprev = vm;

    // ---- packed edge publishes; consumed next body ----
    if (lane == 0)  eL[PW][wv] = make_float2(gv.x, vm.x);
    if (lane == 63) eR[PW][wv] = make_float2(gv.w, vm.w);

    row_barrier();
}

template<bool RE>
__device__ __forceinline__ void sweep(
        const float* __restrict__ ip, float* __restrict__ op, int y0,
        int tid, int lane, int wv, int c0,
        float (*s_img)[SROW], float2 (*eL)[NW], float2 (*eR)[NW]) {
    // constant zero halo columns (in-loop writes cover only [4, Wd+3])
    if (tid < 32) {
        int r = tid >> 3, j = tid & 7;
        int col = (j < 4) ? j : (Wd + j);
        s_img[r][col] = 0.0f;
    }
    // hygiene init of edge buffers (first-body reads feed only never-stored rows)
    if (tid >= 32 && tid < 32 + 2 * NW) {
        int p = (tid - 32) >> 3, w = (tid - 32) & 7;
        eL[p][w] = make_float2(-INFINITY, INFINITY);
        eR[p][w] = make_float2(-INFINITY, INFINITY);
    }

    State S;
    S.gprev = f4s(0.f);
    S.h0 = S.h1 = f4s(-INFINITY);
    S.vmprev = f4s(INFINITY);
    S.n0 = S.n1 = f4s(INFINITY);

    // ---- prime: rows y0-6..y0-1 -> im slots 2..7; rows y0-3..y0-1 -> LDS 1..3
    #pragma unroll
    for (int r = 0; r < 6; ++r) {
        int row = y0 - 6 + r;
        float4 v = f4s(0.f);
        if (!RE || row >= 0) v = *(const float4*)(ip + (size_t)row * Wd);
        S.im[(r + 2) & 7] = v;
        if (r >= 3) *(float4*)&s_img[(r + 2) & 3][c0 + 4] = v;  // slots 1,2,3
    }
    S.im[0] = *(const float4*)(ip + (size_t)y0 * Wd);  // row y0 (always valid)
    S.im[1] = f4s(0.f);                                 // slot for row y0+1
    __syncthreads();

    // ---- warm-up: 7 bodies, no store ----
    row_body<0, RE, false>(y0 + 0, S, ip, op, lane, wv, c0, s_img, eL, eR);
    row_body<1, RE, false>(y0 + 1, S, ip, op, lane, wv, c0, s_img, eL, eR);
    row_body<2, RE, false>(y0 + 2, S, ip, op, lane, wv, c0, s_img, eL, eR);
    row_body<3, RE, false>(y0 + 3, S, ip, op, lane, wv, c0, s_img, eL, eR);
    row_body<4, RE, false>(y0 + 4, S, ip, op, lane, wv, c0, s_img, eL, eR);
    row_body<5, RE, false>(y0 + 5, S, ip, op, lane, wv, c0, s_img, eL, eR);
    row_body<6, RE, false>(y0 + 6, S, ip, op, lane, wv, c0, s_img, eL, eR);

    // ---- steady: CH store bodies (rows y0 .. y0+CH-1), all slots compile-time
    #pragma unroll 1
    for (int jj = 0; jj < CH / 8; ++jj) {
        const int Lb = y0 + 7 + jj * 8;   // Lb % 8 == 7
        row_body<7, RE, true>(Lb + 0, S, ip, op, lane, wv, c0, s_img, eL, eR);
        row_body<0, RE, true>(Lb + 1, S, ip, op, lane, wv, c0, s_img, eL, eR);
        row_body<1, RE, true>(Lb + 2, S, ip, op, lane, wv, c0, s_img, eL, eR);
        row_body<2, RE, true>(Lb + 3, S, ip, op, lane, wv, c0, s_img, eL, eR);
        row_body<3, RE, true>(Lb + 4, S, ip, op, lane, wv, c0, s_img, eL, eR);
        row_body<4, RE, true>(Lb + 5, S, ip, op, lane, wv, c0, s_img, eL, eR);
        row_body<5, RE, true>(Lb + 6, S, ip, op, lane, wv, c0, s_img, eL, eR);
        row_body<6, RE, true>(Lb + 7, S, ip, op, lane, wv, c0, s_img, eL, eR);
    }
}

// 2nd arg = min BLOCKS per CU on this toolchain (r9/r10 decode):
// 4 blocks x 8 waves = 8 waves/SIMD -> VGPR cap 64 (natural 60 fits).
__global__ __launch_bounds__(NT, 4) void gradmap_pipe1d_kernel(
        const float* __restrict__ img, float* __restrict__ out) {
    const int plane = blockIdx.y;
    const int y0 = blockIdx.x * CH;
    const int tid = threadIdx.x;
    const int lane = tid & 63;
    const int wv = tid >> 6;
    const int c0 = tid << 2;
    const float* ip = img + (size_t)plane * Hd * Wd + c0;
    float*       op = out + (size_t)plane * Hd * Wd + c0;

    __shared__ float s_img[4][SROW];
    __shared__ float2 s_eL[2][NW], s_eR[2][NW];  // {grad, vmax} edge pairs

    if (blockIdx.x == 0 || blockIdx.x == gridDim.x - 1)
        sweep<true >(ip, op, y0, tid, lane, wv, c0, s_img, s_eL, s_eR);
    else
        sweep<false>(ip, op, y0, tid, lane, wv, c0, s_img, s_eL, s_eR);
}

extern "C" void kernel_launch(void* const* d_in, const int* in_sizes, int n_in,
                              void* d_out, int out_size, void* d_ws, size_t ws_size,
                              hipStream_t stream) {
    const float* img = (const float*)d_in[0];
    float* out = (float*)d_out;
    dim3 grid(Hd / CH, BC);   // 64 x 24 = 1536 blocks -> 4 co-resident/CU
    dim3 block(NT);
    gradmap_pipe1d_kernel<<<grid, block, 0, stream>>>(img, out);
}